// Round 1
// baseline (391.860 us; speedup 1.0000x reference)
//
#include <hip/hip_runtime.h>
#include <hip/hip_bf16.h>

#define ED 256   // embed dim
#define NW 8     // num weights
#define NR 5     // num relations
#define BM 64    // rows per block

typedef float   f32x4  __attribute__((ext_vector_type(4)));
typedef __bf16  bf16x8 __attribute__((ext_vector_type(8)));
typedef short   short8v __attribute__((ext_vector_type(8)));

__device__ __forceinline__ unsigned short f2bf(float f) {
    return __builtin_bit_cast(unsigned short, __float2bfloat16(f));
}

// ---------------------------------------------------------------------------
// Prep: S_T[r][j][i] = sum_w ws[w,r] * rel[w, i*ED + j]   (bf16, transposed so
// the MFMA B-fragment reads 8 contiguous i (=k) elements for a fixed j (=col))
// ---------------------------------------------------------------------------
__global__ void prep_S(const float* __restrict__ rel,
                       const float* __restrict__ ws,
                       unsigned short* __restrict__ S_T) {
    int idx = blockIdx.x * blockDim.x + threadIdx.x;
    if (idx >= ED * ED) return;
    int i = idx & (ED - 1);
    int j = idx >> 8;
    float acc[NR];
#pragma unroll
    for (int r = 0; r < NR; ++r) acc[r] = 0.f;
#pragma unroll
    for (int w = 0; w < NW; ++w) {
        float rv = rel[(size_t)w * ED * ED + (size_t)i * ED + j];
#pragma unroll
        for (int r = 0; r < NR; ++r) acc[r] += rv * ws[w * NR + r];
    }
#pragma unroll
    for (int r = 0; r < NR; ++r)
        S_T[((size_t)r * ED + j) * ED + i] = f2bf(acc[r]);
}

// ---------------------------------------------------------------------------
// Main: per block, 64 batch rows. For each r: T = e1_tile @ S_r  (MFMA bf16),
// then logit[b,r] = sum_j T[b,j] * e2[b,j] fused in the epilogue.
// 4 waves split the 256 j-columns (64 each) -> no redundant S reads.
// ---------------------------------------------------------------------------
__global__ __launch_bounds__(256, 4) void bilinear_kernel(
    const float* __restrict__ e1, const float* __restrict__ e2,
    const unsigned short* __restrict__ S_T, float* __restrict__ out) {

    __shared__ __align__(16) unsigned short Alds[BM * ED];  // bf16, XOR-swizzled
    __shared__ float Red[BM][4];

    const int t = threadIdx.x;
    const long b0 = (long)blockIdx.x * BM;

    // stage e1 tile: f32 -> bf16, swizzle elem ^= (row&7)<<3 (byte bits 4..6)
#pragma unroll
    for (int u = 0; u < 16; ++u) {
        int idx = u * 256 + t;        // float4 index; 64 float4 per row
        int row = idx >> 6;
        int c4  = idx & 63;
        const float4 v = *(const float4*)(e1 + (b0 + row) * ED + c4 * 4);
        ushort4 p = make_ushort4(f2bf(v.x), f2bf(v.y), f2bf(v.z), f2bf(v.w));
        int col = c4 * 4;
        *(ushort4*)(&Alds[row * ED + (col ^ ((row & 7) << 3))]) = p;
    }
    __syncthreads();

    const int wave = t >> 6;
    const int lane = t & 63;
    const int l15  = lane & 15;
    const int l4   = lane >> 4;

    for (int r = 0; r < NR; ++r) {
        f32x4 acc[4][4];
#pragma unroll
        for (int m = 0; m < 4; ++m)
#pragma unroll
            for (int n = 0; n < 4; ++n)
                acc[m][n] = f32x4{0.f, 0.f, 0.f, 0.f};

        const unsigned short* Sb = S_T + ((size_t)r * ED + wave * 64) * ED;

#pragma unroll
        for (int kb = 0; kb < 8; ++kb) {
            const int kofs = kb * 32 + l4 * 8;
            bf16x8 av[4], bv[4];
#pragma unroll
            for (int m = 0; m < 4; ++m) {
                int row = m * 16 + l15;
                av[m] = __builtin_bit_cast(bf16x8,
                    *(const short8v*)(&Alds[row * ED + (kofs ^ ((row & 7) << 3))]));
            }
#pragma unroll
            for (int n = 0; n < 4; ++n) {
                bv[n] = __builtin_bit_cast(bf16x8,
                    *(const short8v*)(Sb + (size_t)(n * 16 + l15) * ED + kofs));
            }
#pragma unroll
            for (int m = 0; m < 4; ++m)
#pragma unroll
                for (int n = 0; n < 4; ++n)
                    acc[m][n] = __builtin_amdgcn_mfma_f32_16x16x32_bf16(
                        av[m], bv[n], acc[m][n], 0, 0, 0);
        }

        // epilogue: multiply by e2 and reduce over this wave's 64 columns.
        // C frag: row = m*16 + l4*4 + reg, col j = wave*64 + n*16 + l15
        float part[4][4];
#pragma unroll
        for (int m = 0; m < 4; ++m) {
#pragma unroll
            for (int reg = 0; reg < 4; ++reg) {
                int row = m * 16 + l4 * 4 + reg;
                float p = 0.f;
#pragma unroll
                for (int n = 0; n < 4; ++n) {
                    float ev = e2[(b0 + row) * ED + wave * 64 + n * 16 + l15];
                    p += acc[m][n][reg] * ev;
                }
#pragma unroll
                for (int off = 1; off < 16; off <<= 1)
                    p += __shfl_xor(p, off, 64);
                part[m][reg] = p;
            }
        }
        if (l15 == 0) {
#pragma unroll
            for (int m = 0; m < 4; ++m)
#pragma unroll
                for (int reg = 0; reg < 4; ++reg)
                    Red[m * 16 + l4 * 4 + reg][wave] = part[m][reg];
        }
        __syncthreads();
        if (t < BM) {
            float s = Red[t][0] + Red[t][1] + Red[t][2] + Red[t][3];
            out[(b0 + t) * NR + r] = s;
        }
        __syncthreads();
    }
}

extern "C" void kernel_launch(void* const* d_in, const int* in_sizes, int n_in,
                              void* d_out, int out_size, void* d_ws, size_t ws_size,
                              hipStream_t stream) {
    const float* e1  = (const float*)d_in[0];
    const float* e2  = (const float*)d_in[1];
    const float* rel = (const float*)d_in[2];
    const float* ws  = (const float*)d_in[3];
    float* out = (float*)d_out;
    unsigned short* S_T = (unsigned short*)d_ws;  // NR*ED*ED bf16 = 640 KB

    prep_S<<<(ED * ED + 255) / 256, 256, 0, stream>>>(rel, ws, S_T);

    int B = in_sizes[0] / ED;          // 131072
    int grid = B / BM;                 // 2048
    bilinear_kernel<<<grid, 256, 0, stream>>>(e1, e2, S_T, out);
}